// Round 7
// baseline (180.773 us; speedup 1.0000x reference)
//
#include <hip/hip_runtime.h>

#define T_SEQ 4096
#define NDIM 64
#define BH 32
#define TN (T_SEQ * NDIM)

typedef short short8 __attribute__((ext_vector_type(8)));
typedef float f32x16 __attribute__((ext_vector_type(16)));
typedef unsigned uint2e __attribute__((ext_vector_type(2)));

// gfx950: single-op pack of two f32 -> packed bf16x2 (RNE)
static __device__ __forceinline__ unsigned packbf(float lo, float hi) {
    unsigned r;
    asm("v_cvt_pk_bf16_f32 %0, %1, %2" : "=v"(r) : "v"(lo), "v"(hi));
    return r;
}
static __device__ __forceinline__ f32x16 mfma32(short8 a, short8 b, f32x16 c) {
    return __builtin_amdgcn_mfma_f32_32x32x16_bf16(a, b, c, 0, 0, 0);
}

// Cross-half exchange (verified R5/R6)
static __device__ __forceinline__ void half_swap(unsigned &x, unsigned &y) {
#if __has_builtin(__builtin_amdgcn_permlane32_swap)
    uint2e r = __builtin_amdgcn_permlane32_swap(x, y, false, false);
    x = r[0]; y = r[1];
#else
    int sl = (((int)threadIdx.x & 63) ^ 32) << 2;
    unsigned bx = (unsigned)__builtin_amdgcn_ds_bpermute(sl, (int)x);
    unsigned by = (unsigned)__builtin_amdgcn_ds_bpermute(sl, (int)y);
    bool hi = (threadIdx.x & 32) != 0;
    unsigned nx = hi ? by : x;
    unsigned ny = hi ? y : bx;
    x = nx; y = ny;
#endif
}

// 32x32 S^T C-tile -> two A-operand frags (f0: k=s+0..15, f1: k=s+16..31). Verified R5/R6.
static __device__ __forceinline__ void tile_to_frags(const f32x16 &sc, short8 &f0, short8 &f1) {
    unsigned d[4][2];
#pragma unroll
    for (int g = 0; g < 4; ++g) {
        d[g][0] = packbf(sc[4 * g + 0], sc[4 * g + 1]);
        d[g][1] = packbf(sc[4 * g + 2], sc[4 * g + 3]);
    }
    half_swap(d[0][0], d[1][0]);
    half_swap(d[0][1], d[1][1]);
    half_swap(d[2][0], d[3][0]);
    half_swap(d[2][1], d[3][1]);
    union { unsigned u[4]; short8 s; } a, b;
    a.u[0] = d[0][0]; a.u[1] = d[0][1]; a.u[2] = d[1][0]; a.u[3] = d[1][1];
    b.u[0] = d[2][0]; b.u[1] = d[2][1]; b.u[2] = d[3][0]; b.u[3] = d[3][1];
    f0 = a.s; f1 = b.s;
}

// ---------- Kernel 1: RoPE(Q) -> bf16 qf in fragment layout (verified) ----------
__global__ __launch_bounds__(256) void rope_kernel(const float* __restrict__ Q,
                                                   unsigned short* __restrict__ qf) {
    const int bhtb = blockIdx.x;
    const int tb = bhtb & 127;
    const int bh = bhtb >> 7;
    const int np = threadIdx.x & 31;
    const int tg = threadIdx.x >> 5;
    const float freq = exp2f(-0.5f * (float)np) * 0.15915494309189535f;
    const int kc = np >> 3, hi = (np >> 2) & 1, jw = np & 3;
    const float2* qsrc = (const float2*)(Q + ((size_t)bh * T_SEQ + tb * 32) * NDIM);
    unsigned* qdst = (unsigned*)(qf + (size_t)bh * TN + (size_t)tb * 32 * NDIM);
#pragma unroll
    for (int it = 0; it < 4; ++it) {
        const int tl = tg * 4 + it;
        const int t = tb * 32 + tl;
        float2 q = qsrc[tl * 32 + np];
        float ph = (float)t * freq;
        float ang = (ph - floorf(ph)) * 6.283185307179586f;
        float s, c;
        __sincosf(ang, &s, &c);
        float r0 = q.x * c - q.y * s;
        float r1 = q.y * c + q.x * s;
        qdst[kc * 256 + (tl * 2 + hi) * 4 + jw] = packbf(r0, r1);
    }
}

// ---------- Kernel 2: V -> bf16 vfrag (B-frag layout), scaled 0.125 (verified) ----------
__global__ __launch_bounds__(256) void vtrans_kernel(const float* __restrict__ V,
                                                     unsigned short* __restrict__ vfr) {
    __shared__ float tile[128 * 65];
    const int sb = blockIdx.x;
    const int bh = blockIdx.y;
    const int tid = threadIdx.x;
    const float* vsrc = V + ((size_t)bh * T_SEQ + sb * 128) * NDIM;
#pragma unroll
    for (int i = 0; i < 8; ++i) {
        int e = (i * 256 + tid) * 4;
        int row = e >> 6, col = e & 63;
        float4 d4 = *(const float4*)(vsrc + e);
        tile[row * 65 + col + 0] = d4.x; tile[row * 65 + col + 1] = d4.y;
        tile[row * 65 + col + 2] = d4.z; tile[row * 65 + col + 3] = d4.w;
    }
    __syncthreads();
    unsigned short* dst = vfr + (size_t)bh * TN + (size_t)sb * 8192;
#pragma unroll
    for (int u = 0; u < 4; ++u) {
        int g = u * 256 + tid;
        int kc = g >> 7, dh = g & 127;
        int d = dh >> 1, hh = dh & 1;
        int sbase = kc * 16 + hh * 8;
        uint4 o;
        o.x = packbf(tile[(sbase + 0) * 65 + d] * 0.125f, tile[(sbase + 1) * 65 + d] * 0.125f);
        o.y = packbf(tile[(sbase + 2) * 65 + d] * 0.125f, tile[(sbase + 3) * 65 + d] * 0.125f);
        o.z = packbf(tile[(sbase + 4) * 65 + d] * 0.125f, tile[(sbase + 5) * 65 + d] * 0.125f);
        o.w = packbf(tile[(sbase + 6) * 65 + d] * 0.125f, tile[(sbase + 7) * 65 + d] * 0.125f);
        *(uint4*)(dst + g * 8) = o;
    }
}

// ---------- Kernel 3: masked attention — 512 threads, t32/wave, small reg footprint ----------
// Wave (ws,wt): t-tile = t0+32*wt (32 rows); per sb iter, s-range = 128*sb + 64*ws as
// two s32 halves (idx = 2*ws+st2). Per half: 4 S-MFMA -> transform -> 4 O-MFMA.
// No LDS/barriers in the loop; cross-ws reduction once in epilogue.
__global__ __launch_bounds__(512, 3) void attn_kernel(const unsigned short* __restrict__ qf,
                                                      const unsigned short* __restrict__ vfr,
                                                      float* __restrict__ out) {
    __shared__ float4 red[4][2][4][64];   // [wt][dd][g][lane] = 32 KB (epilogue only)

    const int tid = threadIdx.x;
    const int lane = tid & 63;
    const int w = tid >> 6;                 // 0..7
    const int ws = w >> 2, wt = w & 3;
    const int l31 = lane & 31, hi = lane >> 5;

    const int blk = blockIdx.x;
    const int bh = blk & 31;
    const int qb = 31 - (blk >> 5);         // longest q-tiles first
    const int t0 = qb * 128;

    const unsigned short* qfh = qf + (size_t)bh * TN;
    const unsigned short* vfh = vfr + (size_t)bh * TN;
    float* out_h = out + (size_t)bh * TN;

    const int lhx16 = (l31 * 2 + hi) * 8;

    // Persistent Q B-frags for this wave's single t32 tile
    short8 bq[4];
    {
        const int tr32 = (t0 >> 5) + wt;
#pragma unroll
        for (int kc = 0; kc < 4; ++kc)
            bq[kc] = *(const short8*)(qfh + (size_t)(tr32 * 4 + kc) * 512 + lhx16);
    }

    f32x16 oacc[2];   // [dd] : t32 x d64
#pragma unroll
    for (int a = 0; a < 2; ++a)
#pragma unroll
        for (int r = 0; r < 16; ++r) oacc[a][r] = 0.0f;

    for (int sb = 0; sb <= qb; ++sb) {
        const bool diag = (sb == qb);
#pragma unroll
        for (int st2 = 0; st2 < 2; ++st2) {
            const int idx = 2 * ws + st2;            // s32-block index within s128
            if (diag && idx > wt) continue;          // fully masked -> skip

            const int sr32 = sb * 4 + idx;
            // V B-frags for this s32 (issued before S-phase; drain under it)
            short8 vf00 = *(const short8*)(vfh + (size_t)sb * 8192 + (size_t)(2 * idx + 0) * 1024 + lhx16);
            short8 vf01 = *(const short8*)(vfh + (size_t)sb * 8192 + (size_t)(2 * idx + 0) * 1024 + 512 + lhx16);
            short8 vf10 = *(const short8*)(vfh + (size_t)sb * 8192 + (size_t)(2 * idx + 1) * 1024 + lhx16);
            short8 vf11 = *(const short8*)(vfh + (size_t)sb * 8192 + (size_t)(2 * idx + 1) * 1024 + 512 + lhx16);

            // K A-frags
            short8 ak[4];
#pragma unroll
            for (int kc = 0; kc < 4; ++kc)
                ak[kc] = *(const short8*)(qfh + (size_t)(sr32 * 4 + kc) * 512 + lhx16);

            // S-phase: one 32x32 S^T tile (m=s32, n=t32)
            f32x16 sacc;
#pragma unroll
            for (int r = 0; r < 16; ++r) sacc[r] = 0.0f;
#pragma unroll
            for (int kc = 0; kc < 4; ++kc)
                sacc = mfma32(ak[kc], bq[kc], sacc);

            // diagonal mask: zero s >= t
            if (diag && idx == wt) {
                const int tg = l31;                  // within-tile t (tile starts align)
#pragma unroll
                for (int r = 0; r < 16; ++r) {
                    const int sg = (r & 3) + 8 * (r >> 2) + 4 * hi;
                    if (sg >= tg) sacc[r] = 0.0f;
                }
            }

            // C->A transform
            short8 p0, p1;
            tile_to_frags(sacc, p0, p1);

            // O-phase
            oacc[0] = mfma32(p0, vf00, oacc[0]);
            oacc[1] = mfma32(p0, vf01, oacc[1]);
            oacc[0] = mfma32(p1, vf10, oacc[0]);
            oacc[1] = mfma32(p1, vf11, oacc[1]);
        }
    }

    // ---- epilogue: cross-ws partial sum via LDS, then store ----
    if (ws == 1) {
#pragma unroll
        for (int dd = 0; dd < 2; ++dd)
#pragma unroll
            for (int g = 0; g < 4; ++g) {
                float4 v;
                v.x = oacc[dd][4 * g + 0];
                v.y = oacc[dd][4 * g + 1];
                v.z = oacc[dd][4 * g + 2];
                v.w = oacc[dd][4 * g + 3];
                red[wt][dd][g][lane] = v;
            }
    }
    __syncthreads();
    if (ws == 0) {
#pragma unroll
        for (int dd = 0; dd < 2; ++dd) {
#pragma unroll
            for (int g = 0; g < 4; ++g) {
                float4 o = red[wt][dd][g][lane];
                oacc[dd][4 * g + 0] += o.x;
                oacc[dd][4 * g + 1] += o.y;
                oacc[dd][4 * g + 2] += o.z;
                oacc[dd][4 * g + 3] += o.w;
            }
#pragma unroll
            for (int r = 0; r < 16; ++r) {
                const int rl = (r & 3) + 8 * (r >> 2) + 4 * hi;
                out_h[(size_t)(t0 + 32 * wt + rl) * NDIM + 32 * dd + l31] = oacc[dd][r];
            }
        }
    }
}

extern "C" void kernel_launch(void* const* d_in, const int* in_sizes, int n_in,
                              void* d_out, int out_size, void* d_ws, size_t ws_size,
                              hipStream_t stream) {
    (void)in_sizes; (void)n_in; (void)out_size; (void)ws_size;
    const float* Q = (const float*)d_in[0];
    const float* V = (const float*)d_in[1];
    float* out = (float*)d_out;

    unsigned short* qf  = (unsigned short*)d_ws;
    unsigned short* vfr = qf + (size_t)BH * TN;

    rope_kernel<<<BH * 128, 256, 0, stream>>>(Q, qf);
    vtrans_kernel<<<dim3(T_SEQ / 128, BH), 256, 0, stream>>>(V, vfr);
    attn_kernel<<<BH * 32, 512, 0, stream>>>(qf, vfr, out);
}

// Round 8
// 174.223 us; speedup vs baseline: 1.0376x; 1.0376x over previous
//
#include <hip/hip_runtime.h>

#define T_SEQ 4096
#define NDIM 64
#define BH 32
#define TN (T_SEQ * NDIM)

typedef short short8 __attribute__((ext_vector_type(8)));
typedef float f32x16 __attribute__((ext_vector_type(16)));
typedef unsigned uint2e __attribute__((ext_vector_type(2)));

// gfx950: single-op pack of two f32 -> packed bf16x2 (RNE)
static __device__ __forceinline__ unsigned packbf(float lo, float hi) {
    unsigned r;
    asm("v_cvt_pk_bf16_f32 %0, %1, %2" : "=v"(r) : "v"(lo), "v"(hi));
    return r;
}
static __device__ __forceinline__ f32x16 mfma32(short8 a, short8 b, f32x16 c) {
    return __builtin_amdgcn_mfma_f32_32x32x16_bf16(a, b, c, 0, 0, 0);
}

// Cross-half exchange (verified R5/R6)
static __device__ __forceinline__ void half_swap(unsigned &x, unsigned &y) {
#if __has_builtin(__builtin_amdgcn_permlane32_swap)
    uint2e r = __builtin_amdgcn_permlane32_swap(x, y, false, false);
    x = r[0]; y = r[1];
#else
    int sl = (((int)threadIdx.x & 63) ^ 32) << 2;
    unsigned bx = (unsigned)__builtin_amdgcn_ds_bpermute(sl, (int)x);
    unsigned by = (unsigned)__builtin_amdgcn_ds_bpermute(sl, (int)y);
    bool hi = (threadIdx.x & 32) != 0;
    unsigned nx = hi ? by : x;
    unsigned ny = hi ? y : bx;
    x = nx; y = ny;
#endif
}

// 32x32 S^T C-tile -> two A-operand frags (f0: k=s+0..15, f1: k=s+16..31). Verified R5/R6.
static __device__ __forceinline__ void tile_to_frags(const f32x16 &sc, short8 &f0, short8 &f1) {
    unsigned d[4][2];
#pragma unroll
    for (int g = 0; g < 4; ++g) {
        d[g][0] = packbf(sc[4 * g + 0], sc[4 * g + 1]);
        d[g][1] = packbf(sc[4 * g + 2], sc[4 * g + 3]);
    }
    half_swap(d[0][0], d[1][0]);
    half_swap(d[0][1], d[1][1]);
    half_swap(d[2][0], d[3][0]);
    half_swap(d[2][1], d[3][1]);
    union { unsigned u[4]; short8 s; } a, b;
    a.u[0] = d[0][0]; a.u[1] = d[0][1]; a.u[2] = d[1][0]; a.u[3] = d[1][1];
    b.u[0] = d[2][0]; b.u[1] = d[2][1]; b.u[2] = d[3][0]; b.u[3] = d[3][1];
    f0 = a.s; f1 = b.s;
}

// ---------- Kernel 1: RoPE(Q) -> bf16 qf in fragment layout (verified) ----------
__global__ __launch_bounds__(256) void rope_kernel(const float* __restrict__ Q,
                                                   unsigned short* __restrict__ qf) {
    const int bhtb = blockIdx.x;
    const int tb = bhtb & 127;
    const int bh = bhtb >> 7;
    const int np = threadIdx.x & 31;
    const int tg = threadIdx.x >> 5;
    const float freq = exp2f(-0.5f * (float)np) * 0.15915494309189535f;
    const int kc = np >> 3, hi = (np >> 2) & 1, jw = np & 3;
    const float2* qsrc = (const float2*)(Q + ((size_t)bh * T_SEQ + tb * 32) * NDIM);
    unsigned* qdst = (unsigned*)(qf + (size_t)bh * TN + (size_t)tb * 32 * NDIM);
#pragma unroll
    for (int it = 0; it < 4; ++it) {
        const int tl = tg * 4 + it;
        const int t = tb * 32 + tl;
        float2 q = qsrc[tl * 32 + np];
        float ph = (float)t * freq;
        float ang = (ph - floorf(ph)) * 6.283185307179586f;
        float s, c;
        __sincosf(ang, &s, &c);
        float r0 = q.x * c - q.y * s;
        float r1 = q.y * c + q.x * s;
        qdst[kc * 256 + (tl * 2 + hi) * 4 + jw] = packbf(r0, r1);
    }
}

// ---------- Kernel 2: V -> bf16 vfrag (B-frag layout), scaled 0.125 (verified) ----------
__global__ __launch_bounds__(256) void vtrans_kernel(const float* __restrict__ V,
                                                     unsigned short* __restrict__ vfr) {
    __shared__ float tile[128 * 65];
    const int sb = blockIdx.x;
    const int bh = blockIdx.y;
    const int tid = threadIdx.x;
    const float* vsrc = V + ((size_t)bh * T_SEQ + sb * 128) * NDIM;
#pragma unroll
    for (int i = 0; i < 8; ++i) {
        int e = (i * 256 + tid) * 4;
        int row = e >> 6, col = e & 63;
        float4 d4 = *(const float4*)(vsrc + e);
        tile[row * 65 + col + 0] = d4.x; tile[row * 65 + col + 1] = d4.y;
        tile[row * 65 + col + 2] = d4.z; tile[row * 65 + col + 3] = d4.w;
    }
    __syncthreads();
    unsigned short* dst = vfr + (size_t)bh * TN + (size_t)sb * 8192;
#pragma unroll
    for (int u = 0; u < 4; ++u) {
        int g = u * 256 + tid;
        int kc = g >> 7, dh = g & 127;
        int d = dh >> 1, hh = dh & 1;
        int sbase = kc * 16 + hh * 8;
        uint4 o;
        o.x = packbf(tile[(sbase + 0) * 65 + d] * 0.125f, tile[(sbase + 1) * 65 + d] * 0.125f);
        o.y = packbf(tile[(sbase + 2) * 65 + d] * 0.125f, tile[(sbase + 3) * 65 + d] * 0.125f);
        o.z = packbf(tile[(sbase + 4) * 65 + d] * 0.125f, tile[(sbase + 5) * 65 + d] * 0.125f);
        o.w = packbf(tile[(sbase + 6) * 65 + d] * 0.125f, tile[(sbase + 7) * 65 + d] * 0.125f);
        *(uint4*)(dst + g * 8) = o;
    }
}

// ---------- helpers for the pipelined main loop ----------
static __device__ __forceinline__ void load_ak4(const unsigned short* qfh, int sb, int ws,
                                                int lhx16, short8 (&A)[2][4]) {
    const int r32base = sb * 4 + 2 * ws;
#pragma unroll
    for (int st2 = 0; st2 < 2; ++st2)
#pragma unroll
        for (int kc = 0; kc < 4; ++kc)
            A[st2][kc] = *(const short8*)(qfh + (size_t)((r32base + st2) * 4 + kc) * 512 + lhx16);
}
static __device__ __forceinline__ void load_vf8(const unsigned short* vfh, int sb, int ws,
                                                int lhx16, short8 (&V)[4][2]) {
#pragma unroll
    for (int kc4 = 0; kc4 < 4; ++kc4) {
        const size_t base = (size_t)sb * 8192 + (size_t)(4 * ws + kc4) * 1024 + lhx16;
        V[kc4][0] = *(const short8*)(vfh + base);
        V[kc4][1] = *(const short8*)(vfh + base + 512);
    }
}
static __device__ __forceinline__ void s_phase(const short8 (&ak)[2][4], const short8 (&bq)[2][4],
                                               f32x16 (&sacc)[2][2]) {
#pragma unroll
    for (int a = 0; a < 2; ++a)
#pragma unroll
        for (int b = 0; b < 2; ++b)
#pragma unroll
            for (int r = 0; r < 16; ++r) sacc[a][b][r] = 0.0f;
#pragma unroll
    for (int st2 = 0; st2 < 2; ++st2)
#pragma unroll
        for (int tt2 = 0; tt2 < 2; ++tt2)
#pragma unroll
            for (int kc = 0; kc < 4; ++kc)
                sacc[st2][tt2] = mfma32(ak[st2][kc], bq[tt2][kc], sacc[st2][tt2]);
}
static __device__ __forceinline__ void transform_all(const f32x16 (&sacc)[2][2], short8 (&pa)[2][4]) {
#pragma unroll
    for (int st2 = 0; st2 < 2; ++st2)
#pragma unroll
        for (int tt2 = 0; tt2 < 2; ++tt2)
            tile_to_frags(sacc[st2][tt2], pa[tt2][2 * st2 + 0], pa[tt2][2 * st2 + 1]);
}
static __device__ __forceinline__ void o_phase(const short8 (&pa)[2][4], const short8 (&vf)[4][2],
                                               f32x16 (&oacc)[2][2]) {
#pragma unroll
    for (int kc4 = 0; kc4 < 4; ++kc4) {
        oacc[0][0] = mfma32(pa[0][kc4], vf[kc4][0], oacc[0][0]);
        oacc[0][1] = mfma32(pa[0][kc4], vf[kc4][1], oacc[0][1]);
        oacc[1][0] = mfma32(pa[1][kc4], vf[kc4][0], oacc[1][0]);
        oacc[1][1] = mfma32(pa[1][kc4], vf[kc4][1], oacc[1][1]);
    }
}

// ---------- Kernel 3: masked attention — software-pipelined, no LDS in K-loop ----------
// Invariant at loop entry (iter sb): sacc = S^T(sb), ak = frags(sb+1), vf = V(sb).
// Body: transform(sacc)->pa ; S-MFMA(sb+1)->sacc ; O-MFMA(pa,vf)->oacc ; reload ak,vf.
// Diagonal iteration peeled out of the loop (branch-free hot loop).
__global__ __launch_bounds__(256, 2) void attn_kernel(const unsigned short* __restrict__ qf,
                                                      const unsigned short* __restrict__ vfr,
                                                      float* __restrict__ out) {
    __shared__ float4 red[2][4][4][64];   // epilogue only, 32 KB

    const int tid = threadIdx.x;
    const int lane = tid & 63;
    const int w = tid >> 6;
    const int ws = w >> 1, wt = w & 1;
    const int l31 = lane & 31, hi = lane >> 5;

    const int blk = blockIdx.x;
    const int bh = blk & 31;
    const int qb = 31 - (blk >> 5);            // longest q-tiles first
    const int t0 = qb * 128;

    const unsigned short* qfh = qf + (size_t)bh * TN;
    const unsigned short* vfh = vfr + (size_t)bh * TN;
    float* out_h = out + (size_t)bh * TN;

    const int lhx16 = (l31 * 2 + hi) * 8;

    // Persistent Q B-frags (t-range = t0 + 64*wt + 32*tt2)
    short8 bq[2][4];
#pragma unroll
    for (int tt2 = 0; tt2 < 2; ++tt2) {
        const int r32 = (t0 >> 5) + 2 * wt + tt2;
#pragma unroll
        for (int kc = 0; kc < 4; ++kc)
            bq[tt2][kc] = *(const short8*)(qfh + (size_t)(r32 * 4 + kc) * 512 + lhx16);
    }

    f32x16 oacc[2][2];   // [tt2][dd]
#pragma unroll
    for (int a = 0; a < 2; ++a)
#pragma unroll
        for (int b = 0; b < 2; ++b)
#pragma unroll
            for (int r = 0; r < 16; ++r) oacc[a][b][r] = 0.0f;

    // ---- preamble: establish invariant for sb=0 ----
    short8 ak[2][4], vf[4][2];
    f32x16 sacc[2][2];
    load_ak4(qfh, 0, ws, lhx16, ak);
    load_vf8(vfh, 0, ws, lhx16, vf);
    s_phase(ak, bq, sacc);                     // sacc = S(0)
    load_ak4(qfh, (1 <= qb ? 1 : qb), ws, lhx16, ak);   // ak = frags(1)

    // ---- main loop: sb = 0 .. qb-1 (no mask, no branches) ----
    for (int sb = 0; sb < qb; ++sb) {
        short8 pa[2][4];
        transform_all(sacc, pa);               // frees sacc
        s_phase(ak, bq, sacc);                 // sacc = S(sb+1); independent of pa/oacc
        o_phase(pa, vf, oacc);                 // O(sb)
        const int nak = (sb + 2 <= qb) ? sb + 2 : qb;
        load_ak4(qfh, nak, ws, lhx16, ak);     // for S(sb+2)
        load_vf8(vfh, sb + 1, ws, lhx16, vf);  // for O(sb+1)
    }

    // ---- peeled diagonal iteration (sb = qb): mask, transform, O ----
    {
#pragma unroll
        for (int st2 = 0; st2 < 2; ++st2) {
            const int st = 2 * ws + st2;
#pragma unroll
            for (int tt2 = 0; tt2 < 2; ++tt2) {
                const int tg = (2 * wt + tt2) * 32 + l31;
#pragma unroll
                for (int r = 0; r < 16; ++r) {
                    const int sg = st * 32 + (r & 3) + 8 * (r >> 2) + 4 * hi;
                    if (sg >= tg) sacc[st2][tt2][r] = 0.0f;
                }
            }
        }
        short8 pa[2][4];
        transform_all(sacc, pa);
        o_phase(pa, vf, oacc);
    }

    // ---- epilogue: cross-ws partial sum via LDS, then store (verified R6) ----
    if (ws == 1) {
#pragma unroll
        for (int tt2 = 0; tt2 < 2; ++tt2)
#pragma unroll
            for (int dd = 0; dd < 2; ++dd)
#pragma unroll
                for (int g = 0; g < 4; ++g) {
                    float4 v;
                    v.x = oacc[tt2][dd][4 * g + 0];
                    v.y = oacc[tt2][dd][4 * g + 1];
                    v.z = oacc[tt2][dd][4 * g + 2];
                    v.w = oacc[tt2][dd][4 * g + 3];
                    red[wt][tt2 * 2 + dd][g][lane] = v;
                }
    }
    __syncthreads();
    if (ws == 0) {
#pragma unroll
        for (int tt2 = 0; tt2 < 2; ++tt2)
#pragma unroll
            for (int dd = 0; dd < 2; ++dd) {
#pragma unroll
                for (int g = 0; g < 4; ++g) {
                    float4 o = red[wt][tt2 * 2 + dd][g][lane];
                    oacc[tt2][dd][4 * g + 0] += o.x;
                    oacc[tt2][dd][4 * g + 1] += o.y;
                    oacc[tt2][dd][4 * g + 2] += o.z;
                    oacc[tt2][dd][4 * g + 3] += o.w;
                }
#pragma unroll
                for (int r = 0; r < 16; ++r) {
                    const int rl = (r & 3) + 8 * (r >> 2) + 4 * hi;
                    out_h[(size_t)(t0 + 64 * wt + 32 * tt2 + rl) * NDIM + 32 * dd + l31] =
                        oacc[tt2][dd][r];
                }
            }
    }
}

extern "C" void kernel_launch(void* const* d_in, const int* in_sizes, int n_in,
                              void* d_out, int out_size, void* d_ws, size_t ws_size,
                              hipStream_t stream) {
    (void)in_sizes; (void)n_in; (void)out_size; (void)ws_size;
    const float* Q = (const float*)d_in[0];
    const float* V = (const float*)d_in[1];
    float* out = (float*)d_out;

    unsigned short* qf  = (unsigned short*)d_ws;
    unsigned short* vfr = qf + (size_t)BH * TN;

    rope_kernel<<<BH * 128, 256, 0, stream>>>(Q, qf);
    vtrans_kernel<<<dim3(T_SEQ / 128, BH), 256, 0, stream>>>(V, vfr);
    attn_kernel<<<BH * 32, 256, 0, stream>>>(qf, vfr, out);
}